// Round 12
// baseline (88.614 us; speedup 1.0000x reference)
//
#include <hip/hip_runtime.h>
#include <math.h>

constexpr int B_ = 256;
constexpr int D_ = 128;
constexpr int N_ = 65536;
constexpr int P_ = 100;
constexpr int K_ = 4096;
constexpr int P2_ = 10;
constexpr int KP_ = K_ + P_;       // 4196
constexpr int OC_ = P2_ + K_;      // 4106
constexpr int NT_ = 1024;          // 64-row GEMM tiles (row>>6)
constexpr int SLOT_ = 1280;        // per-tile list capacity (mean 1024, sd 32 -> 8 sd)
constexpr int GGEMM_ = 1024;       // gemm blocks [0, 1024)
constexpr int GCOS_ = 256;         // cos blocks  [1024, 1280)
constexpr int GCOPY_ = 1024;       // copy blocks [1280, 2304)
constexpr float T_ = 0.07f;

typedef __attribute__((ext_vector_type(8))) short bf16x8;
typedef __attribute__((ext_vector_type(4))) float f32x4v;

// ---- kernel P: split v2 into bf16 hi/lo; block 32 zeroes gcount ----
__global__ __launch_bounds__(256) void k_prep(
    const float* __restrict__ v2, unsigned short* __restrict__ v2h,
    unsigned short* __restrict__ v2l, int* __restrict__ gcount)
{
  const int tid = threadIdx.x;
  if (blockIdx.x == 32) {                          // zero the 1024 tile counters
    gcount[tid] = 0;
    gcount[tid + 256] = 0;
    gcount[tid + 512] = 0;
    gcount[tid + 768] = 0;
    return;
  }
  const int i4 = blockIdx.x * 256 + tid;           // 8192 float4 total
  const float4 v = reinterpret_cast<const float4*>(v2)[i4];
  const float f[4] = {v.x, v.y, v.z, v.w};
  unsigned short h[4], l[4];
#pragma unroll
  for (int j = 0; j < 4; ++j) {
    const unsigned u = __float_as_uint(f[j]);
    h[j] = (unsigned short)(u >> 16);
    const float al = f[j] - __uint_as_float(u & 0xFFFF0000u);
    l[j] = (unsigned short)(__float_as_uint(al) >> 16);
  }
  ushort4 hv = {h[0], h[1], h[2], h[3]};
  ushort4 lv = {l[0], l[1], l[2], l[3]};
  reinterpret_cast<ushort4*>(v2h)[i4] = hv;
  reinterpret_cast<ushort4*>(v2l)[i4] = lv;
}

// ---- kernel B: bin (b,k) by 64-row tile; emit ptr[b][k] = slot handle ----
// list entry u16 = (rowlocal 6b << 8) | b
__global__ __launch_bounds__(256) void k_bin(
    const int* __restrict__ idx, unsigned short* __restrict__ lists,
    unsigned* __restrict__ ptr, int* __restrict__ gcount)
{
  const int b = blockIdx.x;
  const int tid = threadIdx.x;
  __shared__ int cnt[NT_];
  __shared__ int gbase[NT_];
  for (int t = tid; t < NT_; t += 256) cnt[t] = 0;
  __syncthreads();
  const int4* __restrict__ src = reinterpret_cast<const int4*>(idx + (size_t)b * KP_ + P_);
  unsigned short rows[16];
#pragma unroll
  for (int q = 0; q < 4; ++q) {
    const int4 r = src[q * 256 + tid];
    rows[q * 4 + 0] = (unsigned short)r.x;
    rows[q * 4 + 1] = (unsigned short)r.y;
    rows[q * 4 + 2] = (unsigned short)r.z;
    rows[q * 4 + 3] = (unsigned short)r.w;
    atomicAdd(&cnt[r.x >> 6], 1);
    atomicAdd(&cnt[r.y >> 6], 1);
    atomicAdd(&cnt[r.z >> 6], 1);
    atomicAdd(&cnt[r.w >> 6], 1);
  }
  __syncthreads();
  for (int t = tid; t < NT_; t += 256) {
    const int c = cnt[t];
    gbase[t] = c ? atomicAdd(&gcount[t], c) : 0;
  }
  __syncthreads();
  for (int t = tid; t < NT_; t += 256) cnt[t] = 0;   // reuse as cursor
  __syncthreads();
#pragma unroll
  for (int q = 0; q < 4; ++q) {
#pragma unroll
    for (int u = 0; u < 4; ++u) {
      const int row = rows[q * 4 + u];
      const int tile = row >> 6;
      const int off = atomicAdd(&cnt[tile], 1);
      const int pos = gbase[tile] + off;
      const bool ok = pos < SLOT_;
      const unsigned p = (unsigned)tile * SLOT_ + (unsigned)(ok ? pos : 0);
      if (ok)
        lists[p] = (unsigned short)(((row & 63) << 8) | b);
      ptr[(size_t)b * K_ + (q * 256 + tid) * 4 + u] = p;   // clamped if overflow
    }
  }
}

__device__ inline void split8(const f32x4v lo, const f32x4v hi,
                              bf16x8& h, bf16x8& l) {
#pragma unroll
  for (int j = 0; j < 4; ++j) {
    const unsigned u = __float_as_uint(lo[j]);
    h[j] = (short)(u >> 16);
    const float al = lo[j] - __uint_as_float(u & 0xFFFF0000u);
    l[j] = (short)(__float_as_uint(al) >> 16);
  }
#pragma unroll
  for (int j = 0; j < 4; ++j) {
    const unsigned u = __float_as_uint(hi[j]);
    h[4 + j] = (short)(u >> 16);
    const float al = hi[j] - __uint_as_float(u & 0xFFFF0000u);
    l[4 + j] = (short)(__float_as_uint(al) >> 16);
  }
}

// ---- kernel M: [0,1024) GEMM 64row x 256b + dense-eval epilogue (2 halves);
//                [1024,1280) cos+select; [1280,2304) copy ----
__global__ __launch_bounds__(512, 2) void k_mega(
    const float* __restrict__ v1, const float* __restrict__ v2,
    const int* __restrict__ idx, const float* __restrict__ mem1,
    const float* __restrict__ mem2, const unsigned short* __restrict__ v2h,
    const unsigned short* __restrict__ v2l, const unsigned short* __restrict__ lists,
    const int* __restrict__ gcount, float* __restrict__ evals,
    float* __restrict__ wsel, float* __restrict__ outmem,
    double* __restrict__ wpart)
{
  const int tid = threadIdx.x;
  const unsigned bid = blockIdx.x;
  __shared__ char smem[32768];   // gemm: staging then eval half-tile | cos: aliased
  __shared__ double lacc8[8];

  if (bid < GGEMM_) {
    // ================= GEMM tile (64 rows x 256 b) =================
    const int tile = bid;
    const int r0 = tile * 64;
    {
      const float4* __restrict__ gsrc = reinterpret_cast<const float4*>(mem1 + (size_t)r0 * D_);
#pragma unroll
      for (int q = 0; q < 4; ++q) {
        const int li = q * 512 + tid;              // 2048 float4 total
        const float4 v = gsrc[li];
        const int row = li >> 5;
        const int off = (li & 31) * 16;
        *reinterpret_cast<float4*>(smem + row * 512 + (off ^ ((row & 7) << 4))) = v;
      }
    }
    __syncthreads();
    const int wid = tid >> 6, lane = tid & 63;
    const int mb = (wid >> 1) * 64;                // b-offset of wave tile
    const int nb = (wid & 1) * 32;                 // row-offset of wave tile
    const int klane8 = (lane >> 4) * 8;
    f32x4v acc[4][2];
#pragma unroll
    for (int m = 0; m < 4; ++m)
#pragma unroll
      for (int n = 0; n < 2; ++n) acc[m][n] = {0.f, 0.f, 0.f, 0.f};

    const char* tb = (const char*)smem;
#pragma unroll
    for (int kk = 0; kk < 4; ++kk) {
      const int ks = kk * 32;
      bf16x8 ah[4], al[4];
#pragma unroll
      for (int m = 0; m < 4; ++m) {
        const size_t o = (size_t)(mb + m * 16 + (lane & 15)) * D_ + ks + klane8;
        ah[m] = *reinterpret_cast<const bf16x8*>(v2h + o);
        al[m] = *reinterpret_cast<const bf16x8*>(v2l + o);
      }
#pragma unroll
      for (int n = 0; n < 2; ++n) {
        const int r_loc = nb + n * 16 + (lane & 15);
        const int sw = (r_loc & 7) << 4;
        const int kb = (ks + klane8) * 4;
        const char* rb = tb + r_loc * 512;
        const f32x4v p0 = *reinterpret_cast<const f32x4v*>(rb + ((kb) ^ sw));
        const f32x4v p1 = *reinterpret_cast<const f32x4v*>(rb + ((kb + 16) ^ sw));
        bf16x8 bh, bl;
        split8(p0, p1, bh, bl);
#pragma unroll
        for (int m = 0; m < 4; ++m) {
          acc[m][n] = __builtin_amdgcn_mfma_f32_16x16x32_bf16(ah[m], bh, acc[m][n], 0, 0, 0);
          acc[m][n] = __builtin_amdgcn_mfma_f32_16x16x32_bf16(ah[m], bl, acc[m][n], 0, 0, 0);
          acc[m][n] = __builtin_amdgcn_mfma_f32_16x16x32_bf16(al[m], bh, acc[m][n], 0, 0, 0);
        }
      }
    }
    // ---- epilogue (two b-halves of 128): acc -> LDS [64][128] f32 swizzled,
    //      then walk tile list for that half: exp -> dense evals ----
    __syncthreads();                               // all LDS staging reads done
    const int cntT = min(gcount[tile], SLOT_);
    const unsigned short* __restrict__ lb = lists + (size_t)tile * SLOT_;
    float* __restrict__ eb = evals + (size_t)tile * SLOT_;
    double de = 0.0;
#pragma unroll
    for (int half = 0; half < 2; ++half) {
      if ((mb >> 7) == half) {
#pragma unroll
        for (int m = 0; m < 4; ++m)
#pragma unroll
          for (int n = 0; n < 2; ++n) {
            const int rl = nb + n * 16 + (lane & 15);
            const int b0 = (mb & 64) + m * 16 + (lane >> 4) * 4;   // 0..124
            const float4 vst = {acc[m][n][0], acc[m][n][1], acc[m][n][2], acc[m][n][3]};
            *reinterpret_cast<float4*>(smem + rl * 512 + ((b0 * 4) ^ ((rl & 7) << 4))) = vst;
          }
      }
      __syncthreads();
      for (int i = tid; i < cntT; i += 512) {
        const int e = lb[i];
        const int bb = e & 255;
        if ((bb >> 7) == half) {
          const int rl = e >> 8;
          const float s = *reinterpret_cast<const float*>(
              smem + rl * 512 + (((bb & 127) * 4) ^ ((rl & 7) << 4)));
          const float ex = expf(s * (1.0f / T_));
          eb[i] = ex;
          de += (double)ex;
        }
      }
      __syncthreads();
    }
#pragma unroll
    for (int sh = 1; sh < 64; sh <<= 1) de += __shfl_xor(de, sh);
    if (lane == 0) lacc8[wid] = de;
    __syncthreads();
    if (tid == 0) {
      double s = 0.0;
#pragma unroll
      for (int w = 0; w < 8; ++w) s += lacc8[w];
      wpart[tile] = s;
    }
  } else if (bid < GGEMM_ + GCOS_) {
    // ================= cosine path (r < P) + stable top-10 =================
    float* sbuf = (float*)smem;                      // 2*D floats
    double* sdiff = (double*)(smem + 1024);          // P doubles
    float* swout = (float*)(smem + 1024 + 800);      // P floats
    double* dsn2 = (double*)(smem + 1024 + 800 + 416);
    double* dss = (double*)(smem + 1024 + 800 + 416 + 800);
    double* dinv = (double*)(smem + 1024 + 800 + 416 + 1600);
    const int b = bid - GGEMM_;
    if (tid < 32)
      reinterpret_cast<float4*>(sbuf)[tid] =
          reinterpret_cast<const float4*>(v2 + (size_t)b * D_)[tid];
    else if (tid < 64)
      reinterpret_cast<float4*>(sbuf)[tid] =
          reinterpret_cast<const float4*>(v1 + (size_t)b * D_)[tid - 32];
    __syncthreads();
    if (tid < 64) {
      const float2* s2 = reinterpret_cast<const float2*>(sbuf);
      const float2 a = s2[tid];
      const float2 c = s2[64 + tid];
      double dn2 = (double)a.x * a.x + (double)a.y * a.y;
      double dn1 = (double)c.x * c.x + (double)c.y * c.y;
#pragma unroll
      for (int sh = 1; sh < 64; sh <<= 1) {
        dn2 += __shfl_xor(dn2, sh);
        dn1 += __shfl_xor(dn1, sh);
      }
      if (tid == 0) { dinv[0] = 1.0 / sqrt(dn1); dinv[1] = 1.0 / sqrt(dn2); }
    }
    if (tid >= 128 && tid < 128 + P_) {
      const int r = tid - 128;
      const int row = idx[(size_t)b * KP_ + r];
      const float4* __restrict__ w2p = reinterpret_cast<const float4*>(mem2 + (size_t)row * D_);
      const float4* __restrict__ x2p = reinterpret_cast<const float4*>(sbuf);
      double sn2 = 0, ss = 0;
#pragma unroll 4
      for (int jj = 0; jj < 32; ++jj) {
        const float4 cc = w2p[jj];
        const float4 y2 = x2p[jj];
        sn2 += (double)cc.x * cc.x + (double)cc.y * cc.y + (double)cc.z * cc.z + (double)cc.w * cc.w;
        ss  += (double)cc.x * y2.x + (double)cc.y * y2.y + (double)cc.z * y2.z + (double)cc.w * y2.w;
      }
      dsn2[r] = sn2; dss[r] = ss;
    }
    double so = 0, sn1 = 0, st = 0;
    if (tid < P_) {
      const int row = idx[(size_t)b * KP_ + tid];
      const float4* __restrict__ w1p = reinterpret_cast<const float4*>(mem1 + (size_t)row * D_);
      const float4* __restrict__ x2p = reinterpret_cast<const float4*>(sbuf);
      const float4* __restrict__ x1p = reinterpret_cast<const float4*>(sbuf + D_);
#pragma unroll 4
      for (int jj = 0; jj < 32; ++jj) {
        const float4 a  = w1p[jj];
        const float4 y1 = x1p[jj];
        const float4 y2 = x2p[jj];
        so  += (double)a.x * y2.x + (double)a.y * y2.y + (double)a.z * y2.z + (double)a.w * y2.w;
        sn1 += (double)a.x * a.x  + (double)a.y * a.y  + (double)a.z * a.z  + (double)a.w * a.w;
        st  += (double)a.x * y1.x + (double)a.y * y1.y + (double)a.z * y1.z + (double)a.w * y1.w;
      }
    }
    __syncthreads();
    if (tid < P_) {
      const double t_rel = st * dinv[0] / sqrt(sn1);
      const double s_rel = dss[tid] * dinv[1] / sqrt(dsn2[tid]);
      sdiff[tid] = t_rel - s_rel;
      swout[tid] = expf((float)(so * (1.0 / (double)T_)));
    }
    __syncthreads();
    if (tid < 64) {
      const int l = tid;
      const double va = sdiff[l];
      const double vb = (l < P_ - 64) ? sdiff[l + 64] : -1.0e300;
      bool ta = false, tb2 = (l >= P_ - 64);
      int sel[P2_];
#pragma unroll
      for (int t = 0; t < P2_; ++t) {
        double cv; int cj;
        const bool aok = !ta, bok = !tb2;
        if (aok && (!bok || va >= vb)) { cv = va; cj = l; }
        else if (bok)                  { cv = vb; cj = l + 64; }
        else                           { cv = -1.0e300; cj = 0x7fffffff; }
#pragma unroll
        for (int sh = 1; sh < 64; sh <<= 1) {
          const double ov = __shfl_xor(cv, sh);
          const int    oj = __shfl_xor(cj, sh);
          if (ov > cv || (ov == cv && oj < cj)) { cv = ov; cj = oj; }
        }
        sel[t] = cj;
        if (cj == l) ta = true;
        if (cj == l + 64) tb2 = true;
      }
      if (l == 0) {
        sel[0] = 0;  // .at[:,0].set(0) applied AFTER taking top-P2
        double sp = 0.0;
#pragma unroll
        for (int t = 0; t < P2_; ++t) {
          const float e = swout[sel[t]];
          wsel[b * P2_ + t] = e;  // unnormalized
          sp += (double)e;
        }
        wpart[GGEMM_ + b] = sp;
      }
    }
  } else {
    // ================= copy memory_v1 -> outmem (32 KB/block) =============
    const int g = bid - GGEMM_ - GCOS_;
    const float4* __restrict__ s4 = reinterpret_cast<const float4*>(mem1) + (size_t)g * 2048;
    float4* __restrict__ d4 = reinterpret_cast<float4*>(outmem) + (size_t)g * 2048;
#pragma unroll
    for (int i = 0; i < 4; ++i) d4[i * 512 + tid] = s4[i * 512 + tid];
  }
}

// ---- kernel O: self-reduce Z, gather evals via ptr -> out (scaled),
//                place top-10, y-row update. 512 blocks (b, half). ----
__global__ __launch_bounds__(256) void k_out(
    const unsigned* __restrict__ ptr, const float* __restrict__ evals,
    const float* __restrict__ wsel, const double* __restrict__ wpart,
    const float* __restrict__ mem1, const float* __restrict__ v1,
    const int* __restrict__ y, float* __restrict__ out,
    float* __restrict__ outmem)
{
  const int b = blockIdx.x >> 1;
  const int half = blockIdx.x & 1;
  const int tid = threadIdx.x;
  __shared__ double lds[4];
  __shared__ float scs;
  double s = 0.0;
  for (int i = tid; i < GGEMM_ + GCOS_; i += 256) s += wpart[i];
#pragma unroll
  for (int sh = 1; sh < 64; sh <<= 1) s += __shfl_xor(s, sh);
  if ((tid & 63) == 0) lds[tid >> 6] = s;
  __syncthreads();
  if (tid == 0) {
    const double S = (lds[0] + lds[1]) + (lds[2] + lds[3]);
    const double Z = S / ((double)B_ * (double)OC_) * (double)N_;
    scs = (float)(1.0 / Z);
  }
  __syncthreads();
  const float sc = scs;
  const unsigned* __restrict__ pb = ptr + (size_t)b * K_ + half * 2048;
  float* __restrict__ orow = out + (size_t)b * OC_ + P2_ + half * 2048;
#pragma unroll
  for (int j = 0; j < 8; ++j) {
    const int k = j * 256 + tid;
    const unsigned p = pb[k];
    orow[k] = evals[p] * sc;
  }
  if (half == 0) {
    if (tid < P2_) out[(size_t)b * OC_ + tid] = wsel[b * P2_ + tid] * sc;
    if (tid >= 64 && tid < 128) {
      const int lane = tid - 64;
      const int row = y[b];
      const float2 m = *reinterpret_cast<const float2*>(mem1 + (size_t)row * D_ + lane * 2);
      const float2 a = *reinterpret_cast<const float2*>(v1 + (size_t)b * D_ + lane * 2);
      float2 l;
      l.x = m.x * 0.5f + a.x * 0.5f;
      l.y = m.y * 0.5f + a.y * 0.5f;
      float n = l.x * l.x + l.y * l.y;
#pragma unroll
      for (int sh = 1; sh < 64; sh <<= 1) n += __shfl_xor(n, sh);
      const float inv = 1.0f / sqrtf(n);
      float2 o;
      o.x = l.x * inv;
      o.y = l.y * inv;
      *reinterpret_cast<float2*>(outmem + (size_t)row * D_ + lane * 2) = o;
    }
  }
}

extern "C" void kernel_launch(void* const* d_in, const int* in_sizes, int n_in,
                              void* d_out, int out_size, void* d_ws, size_t ws_size,
                              hipStream_t stream) {
  // setup_inputs order: epoch, v1, v2, y, idx, memory_v1, memory_v2
  const float* v1   = (const float*)d_in[1];
  const float* v2   = (const float*)d_in[2];
  const int*   y    = (const int*)d_in[3];
  const int*   idx  = (const int*)d_in[4];
  const float* mem1 = (const float*)d_in[5];
  const float* mem2 = (const float*)d_in[6];

  float* out    = (float*)d_out;                      // (B, P2+K) scores
  float* outmem = out + (size_t)B_ * OC_;             // (N, D) new memory

  char* ws = (char*)d_ws;
  double*         wpart  = (double*)ws;                          // 1280 doubles
  float*          wsel   = (float*)(ws + 16384);                 // B*P2 floats
  int*            gcount = (int*)(ws + 32768);                   // 1024 ints
  unsigned short* v2h    = (unsigned short*)(ws + 40960);        // 64 KB
  unsigned short* v2l    = (unsigned short*)(ws + 40960 + 65536);
  unsigned short* lists  = (unsigned short*)(ws + 40960 + 2 * 65536);          // 2.62 MB
  float*          evals  = (float*)(ws + 40960 + 2 * 65536 + 2621440);         // 5.24 MB
  unsigned*       ptr    = (unsigned*)(ws + 40960 + 2 * 65536 + 2621440 + 5242880);  // 4.19 MB

  k_prep<<<33, 256, 0, stream>>>(v2, v2h, v2l, gcount);
  k_bin<<<B_, 256, 0, stream>>>(idx, lists, ptr, gcount);
  k_mega<<<GGEMM_ + GCOS_ + GCOPY_, 512, 0, stream>>>(
      v1, v2, idx, mem1, mem2, v2h, v2l, lists, gcount, evals, wsel, outmem, wpart);
  k_out<<<2 * B_, 256, 0, stream>>>(ptr, evals, wsel, wpart, mem1, v1, y,
                                    out, outmem);
}

// Round 13
// 64.626 us; speedup vs baseline: 1.3712x; 1.3712x over previous
//
#include <hip/hip_runtime.h>
#include <math.h>

constexpr int B_ = 256;
constexpr int D_ = 128;
constexpr int N_ = 65536;
constexpr int P_ = 100;
constexpr int K_ = 4096;
constexpr int P2_ = 10;
constexpr int KP_ = K_ + P_;       // 4196
constexpr int OC_ = P2_ + K_;      // 4106
constexpr int NBIN_ = 8;           // row>>13 -> 8 bins of 4 MB (one XCD L2 each)
constexpr int SLOT_ = 768;         // capacity per (b,bin); mean 512, sd 21 -> 12 sd slack
constexpr int GCOS_ = B_;          // cos+select  [0, 256)    -- longest pole first
constexpr int GCOPY_ = 2048;       // copy        [256, 2304) -- primes L2 slices
constexpr int GGATH_ = B_ * NBIN_; // gather      [2304, 4352)
constexpr int NPART_ = GGATH_ + B_;  // 2304 partial-sum slots
constexpr float T_ = 0.07f;

// ---------------- kernel 0: bin the negatives' indices ----------------
__global__ __launch_bounds__(256) void k_bin(
    const int* __restrict__ idx, unsigned* __restrict__ lists,
    int* __restrict__ counts)
{
  const int b = blockIdx.x;
  const int tid = threadIdx.x;
  __shared__ int cnt[NBIN_];
  if (tid < NBIN_) cnt[tid] = 0;
  __syncthreads();
  const int4* __restrict__ src = reinterpret_cast<const int4*>(idx + (size_t)b * KP_ + P_);
#pragma unroll
  for (int i = 0; i < 4; ++i) {
    const int4 r4 = src[i * 256 + tid];
    const int ks = (i * 256 + tid) * 4;
    const int rows[4] = {r4.x, r4.y, r4.z, r4.w};
#pragma unroll
    for (int u = 0; u < 4; ++u) {
      const int row = rows[u];
      const int bin = row >> 13;
      const int slot = atomicAdd(&cnt[bin], 1);
      if (slot < SLOT_)
        lists[((size_t)(b * NBIN_ + bin)) * SLOT_ + slot] =
            ((unsigned)(ks + u) << 16) | (unsigned)row;
    }
  }
  __syncthreads();
  if (tid < NBIN_) counts[b * NBIN_ + tid] = min(cnt[tid], SLOT_);
}

// -------- kernel 1: fused cos/select + copy + binned gather (dense e) -----
__global__ __launch_bounds__(256) void k_main(
    const float* __restrict__ v1, const float* __restrict__ v2,
    const int* __restrict__ idx, const float* __restrict__ mem1,
    const float* __restrict__ mem2, const unsigned* __restrict__ lists,
    const int* __restrict__ counts, float* __restrict__ evals,
    float* __restrict__ wsel, float* __restrict__ outmem,
    double* __restrict__ wpart)
{
  const int tid = threadIdx.x;
  const unsigned bid = blockIdx.x;
  __shared__ double lacc[4];
  __shared__ float sbuf[2 * D_];
  __shared__ double sdiff[P_];
  __shared__ float swout[P_];
  __shared__ double dsn2[P_], dss[P_];
  __shared__ double dinv[2];

  if (bid < GCOS_) {
    // ---- cosine path: w1-dots on tid<100, w2-dots on tid in [128,228) ----
    const int b = bid;
    if (tid < 32)
      reinterpret_cast<float4*>(sbuf)[tid] =             // sbuf[0..127] = v2[b]
          reinterpret_cast<const float4*>(v2 + (size_t)b * D_)[tid];
    else if (tid < 64)
      reinterpret_cast<float4*>(sbuf)[tid] =             // sbuf[128..255] = v1[b]
          reinterpret_cast<const float4*>(v1 + (size_t)b * D_)[tid - 32];
    __syncthreads();
    if (tid < 64) {                                      // wave-parallel norms
      const float2* s2 = reinterpret_cast<const float2*>(sbuf);
      const float2 a = s2[tid];        // v2 elems
      const float2 c = s2[64 + tid];   // v1 elems
      double dn2 = (double)a.x * a.x + (double)a.y * a.y;
      double dn1 = (double)c.x * c.x + (double)c.y * c.y;
#pragma unroll
      for (int sh = 1; sh < 64; sh <<= 1) {
        dn2 += __shfl_xor(dn2, sh);
        dn1 += __shfl_xor(dn1, sh);
      }
      if (tid == 0) { dinv[0] = 1.0 / sqrt(dn1); dinv[1] = 1.0 / sqrt(dn2); }
    }
    if (tid >= 128 && tid < 128 + P_) {                  // w2: sn2, ss
      const int r = tid - 128;
      const int row = idx[(size_t)b * KP_ + r];
      const float4* __restrict__ w2p = reinterpret_cast<const float4*>(mem2 + (size_t)row * D_);
      const float4* __restrict__ x2p = reinterpret_cast<const float4*>(sbuf);
      double sn2 = 0, ss = 0;
#pragma unroll 4
      for (int jj = 0; jj < 32; ++jj) {
        const float4 cc = w2p[jj];
        const float4 y2 = x2p[jj];
        sn2 += (double)cc.x * cc.x + (double)cc.y * cc.y + (double)cc.z * cc.z + (double)cc.w * cc.w;
        ss  += (double)cc.x * y2.x + (double)cc.y * y2.y + (double)cc.z * y2.z + (double)cc.w * y2.w;
      }
      dsn2[r] = sn2; dss[r] = ss;
    }
    double so = 0, sn1 = 0, st = 0;
    if (tid < P_) {                                      // w1: so, sn1, st
      const int row = idx[(size_t)b * KP_ + tid];
      const float4* __restrict__ w1p = reinterpret_cast<const float4*>(mem1 + (size_t)row * D_);
      const float4* __restrict__ x2p = reinterpret_cast<const float4*>(sbuf);
      const float4* __restrict__ x1p = reinterpret_cast<const float4*>(sbuf + D_);
#pragma unroll 4
      for (int jj = 0; jj < 32; ++jj) {
        const float4 a  = w1p[jj];
        const float4 y1 = x1p[jj];
        const float4 y2 = x2p[jj];
        so  += (double)a.x * y2.x + (double)a.y * y2.y + (double)a.z * y2.z + (double)a.w * y2.w;
        sn1 += (double)a.x * a.x  + (double)a.y * a.y  + (double)a.z * a.z  + (double)a.w * a.w;
        st  += (double)a.x * y1.x + (double)a.y * y1.y + (double)a.z * y1.z + (double)a.w * y1.w;
      }
    }
    __syncthreads();
    if (tid < P_) {
      const double t_rel = st * dinv[0] / sqrt(sn1);
      const double s_rel = dss[tid] * dinv[1] / sqrt(dsn2[tid]);
      sdiff[tid] = t_rel - s_rel;
      swout[tid] = expf((float)(so * (1.0 / (double)T_)));
    }
    __syncthreads();
    if (tid < 64) {
      // stable top-10: butterfly argmax under (value desc, index asc)
      const int l = tid;
      const double va = sdiff[l];
      const double vb = (l < P_ - 64) ? sdiff[l + 64] : -1.0e300;
      bool ta = false, tb = (l >= P_ - 64);
      int sel[P2_];
#pragma unroll
      for (int t = 0; t < P2_; ++t) {
        double cv; int cj;
        const bool aok = !ta, bok = !tb;
        if (aok && (!bok || va >= vb)) { cv = va; cj = l; }
        else if (bok)                  { cv = vb; cj = l + 64; }
        else                           { cv = -1.0e300; cj = 0x7fffffff; }
#pragma unroll
        for (int sh = 1; sh < 64; sh <<= 1) {
          const double ov = __shfl_xor(cv, sh);
          const int    oj = __shfl_xor(cj, sh);
          if (ov > cv || (ov == cv && oj < cj)) { cv = ov; cj = oj; }
        }
        sel[t] = cj;
        if (cj == l) ta = true;
        if (cj == l + 64) tb = true;
      }
      if (l == 0) {
        sel[0] = 0;  // .at[:,0].set(0) applied AFTER taking top-P2
        double sp = 0.0;
#pragma unroll
        for (int t = 0; t < P2_; ++t) {
          const float e = swout[sel[t]];
          wsel[b * P2_ + t] = e;  // unnormalized
          sp += (double)e;
        }
        wpart[GGATH_ + b] = sp;
      }
    }
  } else if (bid < GCOS_ + GCOPY_) {
    // ---- copy memory_v1 -> outmem, bin-aligned (primes L2 slices) ----
    const int g = bid - GCOS_;
    const int r = g & 7, q = g >> 3;
    const size_t base = ((size_t)r * 8192 + (size_t)q * 32) * D_;  // 32 rows = 16 KB
    const float4* __restrict__ s = reinterpret_cast<const float4*>(mem1 + base);
    float4* __restrict__ d = reinterpret_cast<float4*>(outmem + base);
#pragma unroll
    for (int i = 0; i < 4; ++i) d[i * 256 + tid] = s[i * 256 + tid];
  } else {
    // ---- binned gather dots: 8 lanes/row, 4 rows in flight, dense e out ----
    const int g = bid - GCOS_ - GCOPY_;
    const int bin = g & 7, b = g >> 3;
    const int count = counts[b * NBIN_ + bin];
    const unsigned* __restrict__ lb = lists + ((size_t)(b * NBIN_ + bin)) * SLOT_;
    float* __restrict__ eb = evals + ((size_t)(b * NBIN_ + bin)) * SLOT_;
    const int j = tid & 7, gg = tid >> 3;
    const float4* __restrict__ v2p = reinterpret_cast<const float4*>(v2 + (size_t)b * D_);
    const float4 x0 = v2p[j], x1 = v2p[j + 8], x2 = v2p[j + 16], x3 = v2p[j + 24];

    double de = 0.0;
    int s = gg;
    for (; s + 96 < count; s += 128) {            // 4 rows in flight per group
      const unsigned e0 = lb[s];
      const unsigned e1 = lb[s + 32];
      const unsigned e2 = lb[s + 64];
      const unsigned e3 = lb[s + 96];
      const float4* __restrict__ p0 = reinterpret_cast<const float4*>(mem1 + (size_t)(e0 & 0xFFFFu) * D_);
      const float4* __restrict__ p1 = reinterpret_cast<const float4*>(mem1 + (size_t)(e1 & 0xFFFFu) * D_);
      const float4* __restrict__ p2 = reinterpret_cast<const float4*>(mem1 + (size_t)(e2 & 0xFFFFu) * D_);
      const float4* __restrict__ p3 = reinterpret_cast<const float4*>(mem1 + (size_t)(e3 & 0xFFFFu) * D_);
      const float4 a0 = p0[j], a1 = p0[j + 8], a2 = p0[j + 16], a3 = p0[j + 24];
      const float4 b0 = p1[j], b1 = p1[j + 8], b2 = p1[j + 16], b3 = p1[j + 24];
      const float4 c0 = p2[j], c1 = p2[j + 8], c2 = p2[j + 16], c3 = p2[j + 24];
      const float4 d0 = p3[j], d1 = p3[j + 8], d2 = p3[j + 16], d3 = p3[j + 24];
      float s0 = a0.x * x0.x + a0.y * x0.y + a0.z * x0.z + a0.w * x0.w
               + a1.x * x1.x + a1.y * x1.y + a1.z * x1.z + a1.w * x1.w
               + a2.x * x2.x + a2.y * x2.y + a2.z * x2.z + a2.w * x2.w
               + a3.x * x3.x + a3.y * x3.y + a3.z * x3.z + a3.w * x3.w;
      float s1 = b0.x * x0.x + b0.y * x0.y + b0.z * x0.z + b0.w * x0.w
               + b1.x * x1.x + b1.y * x1.y + b1.z * x1.z + b1.w * x1.w
               + b2.x * x2.x + b2.y * x2.y + b2.z * x2.z + b2.w * x2.w
               + b3.x * x3.x + b3.y * x3.y + b3.z * x3.z + b3.w * x3.w;
      float s2v = c0.x * x0.x + c0.y * x0.y + c0.z * x0.z + c0.w * x0.w
                + c1.x * x1.x + c1.y * x1.y + c1.z * x1.z + c1.w * x1.w
                + c2.x * x2.x + c2.y * x2.y + c2.z * x2.z + c2.w * x2.w
                + c3.x * x3.x + c3.y * x3.y + c3.z * x3.z + c3.w * x3.w;
      float s3v = d0.x * x0.x + d0.y * x0.y + d0.z * x0.z + d0.w * x0.w
                + d1.x * x1.x + d1.y * x1.y + d1.z * x1.z + d1.w * x1.w
                + d2.x * x2.x + d2.y * x2.y + d2.z * x2.z + d2.w * x2.w
                + d3.x * x3.x + d3.y * x3.y + d3.z * x3.z + d3.w * x3.w;
#pragma unroll
      for (int sh = 1; sh < 8; sh <<= 1) {
        s0 += __shfl_xor(s0, sh);
        s1 += __shfl_xor(s1, sh);
        s2v += __shfl_xor(s2v, sh);
        s3v += __shfl_xor(s3v, sh);
      }
      if (j == 0) {
        const float f0 = expf(s0 * (1.0f / T_));
        const float f1 = expf(s1 * (1.0f / T_));
        const float f2 = expf(s2v * (1.0f / T_));
        const float f3 = expf(s3v * (1.0f / T_));
        eb[s] = f0; eb[s + 32] = f1; eb[s + 64] = f2; eb[s + 96] = f3;  // dense, coalesced
        de += ((double)f0 + (double)f1) + ((double)f2 + (double)f3);
      }
    }
    for (; s < count; s += 32) {                  // tail
      const unsigned e0 = lb[s];
      const float4* __restrict__ p0 = reinterpret_cast<const float4*>(mem1 + (size_t)(e0 & 0xFFFFu) * D_);
      const float4 a0 = p0[j], a1 = p0[j + 8], a2 = p0[j + 16], a3 = p0[j + 24];
      float s0 = a0.x * x0.x + a0.y * x0.y + a0.z * x0.z + a0.w * x0.w
               + a1.x * x1.x + a1.y * x1.y + a1.z * x1.z + a1.w * x1.w
               + a2.x * x2.x + a2.y * x2.y + a2.z * x2.z + a2.w * x2.w
               + a3.x * x3.x + a3.y * x3.y + a3.z * x3.z + a3.w * x3.w;
#pragma unroll
      for (int sh = 1; sh < 8; sh <<= 1) s0 += __shfl_xor(s0, sh);
      if (j == 0) {
        const float f0 = expf(s0 * (1.0f / T_));
        eb[s] = f0;
        de += (double)f0;
      }
    }
#pragma unroll
    for (int sh = 1; sh < 64; sh <<= 1) de += __shfl_xor(de, sh);
    if ((tid & 63) == 0) lacc[tid >> 6] = de;
    __syncthreads();
    if (tid == 0) wpart[g] = (lacc[0] + lacc[1]) + (lacc[2] + lacc[3]);
  }
}

// -------- kernel 2: self-reduce Z, permute dense e -> out (scaled),
//          place top-10, y-row update. One block per b. --------
__global__ __launch_bounds__(256) void k_out(
    const unsigned* __restrict__ lists, const int* __restrict__ counts,
    const float* __restrict__ evals, const float* __restrict__ wsel,
    const double* __restrict__ wpart, const float* __restrict__ mem1,
    const float* __restrict__ v1, const int* __restrict__ y,
    float* __restrict__ out, float* __restrict__ outmem)
{
  __shared__ float srow[K_];  // 16 KB
  __shared__ double lds[4];
  __shared__ float scs;
  const int b = blockIdx.x;
  const int tid = threadIdx.x;
  // ---- Z self-reduction (all NPART_ partials) ----
  double zs = 0.0;
  for (int i = tid; i < NPART_; i += 256) zs += wpart[i];
#pragma unroll
  for (int sh = 1; sh < 64; sh <<= 1) zs += __shfl_xor(zs, sh);
  if ((tid & 63) == 0) lds[tid >> 6] = zs;
  __syncthreads();
  if (tid == 0) {
    const double S = (lds[0] + lds[1]) + (lds[2] + lds[3]);
    const double Z = S / ((double)B_ * (double)OC_) * (double)N_;
    scs = (float)(1.0 / Z);
  }
  // ---- permute dense evals into srow while Z finishes ----
#pragma unroll
  for (int bin = 0; bin < NBIN_; ++bin) {
    const int cnt = counts[b * NBIN_ + bin];
    const unsigned* __restrict__ lb = lists + ((size_t)(b * NBIN_ + bin)) * SLOT_;
    const float* __restrict__ eb = evals + ((size_t)(b * NBIN_ + bin)) * SLOT_;
    for (int s = tid; s < cnt; s += 256) srow[lb[s] >> 16] = eb[s];
  }
  __syncthreads();
  const float sc = scs;
  float* __restrict__ orow = out + (size_t)b * OC_;
  if (tid < P2_) orow[tid] = wsel[b * P2_ + tid] * sc;
  for (int i = tid; i < K_; i += 256) orow[P2_ + i] = srow[i] * sc;
  if (tid < 64) {
    // y-row momentum update + normalize (overwrites copied row)
    const int row = y[b];
    const float2 m = *reinterpret_cast<const float2*>(mem1 + (size_t)row * D_ + tid * 2);
    const float2 a = *reinterpret_cast<const float2*>(v1 + (size_t)b * D_ + tid * 2);
    float2 l;
    l.x = m.x * 0.5f + a.x * 0.5f;
    l.y = m.y * 0.5f + a.y * 0.5f;
    float n = l.x * l.x + l.y * l.y;
#pragma unroll
    for (int sh = 1; sh < 64; sh <<= 1) n += __shfl_xor(n, sh);
    const float inv = 1.0f / sqrtf(n);
    float2 o;
    o.x = l.x * inv;
    o.y = l.y * inv;
    *reinterpret_cast<float2*>(outmem + (size_t)row * D_ + tid * 2) = o;
  }
}

extern "C" void kernel_launch(void* const* d_in, const int* in_sizes, int n_in,
                              void* d_out, int out_size, void* d_ws, size_t ws_size,
                              hipStream_t stream) {
  // setup_inputs order: epoch, v1, v2, y, idx, memory_v1, memory_v2
  const float* v1   = (const float*)d_in[1];
  const float* v2   = (const float*)d_in[2];
  const int*   y    = (const int*)d_in[3];
  const int*   idx  = (const int*)d_in[4];
  const float* mem1 = (const float*)d_in[5];
  const float* mem2 = (const float*)d_in[6];

  float* out    = (float*)d_out;                      // (B, P2+K) scores
  float* outmem = out + (size_t)B_ * OC_;             // (N, D) new memory

  char* ws = (char*)d_ws;
  constexpr size_t LSZ = (size_t)B_ * NBIN_ * SLOT_ * 4;         // 6,291,456 B
  double*   wpart  = (double*)ws;                                // NPART_ doubles (18,432 B)
  int*      counts = (int*)(ws + 32768);                         // B*8 ints (8,192 B)
  unsigned* lists  = (unsigned*)(ws + 65536);                    // LSZ bytes
  float*    evals  = (float*)(ws + 65536 + LSZ);                 // LSZ bytes
  float*    wsel   = (float*)(ws + 65536 + 2 * LSZ);             // B*P2 floats

  k_bin<<<B_, 256, 0, stream>>>(idx, lists, counts);
  k_main<<<GCOS_ + GCOPY_ + GGATH_, 256, 0, stream>>>(
      v1, v2, idx, mem1, mem2, lists, counts, evals, wsel, outmem, wpart);
  k_out<<<B_, 256, 0, stream>>>(lists, counts, evals, wsel, wpart,
                                mem1, v1, y, out, outmem);
}